// Round 9
// baseline (383.015 us; speedup 1.0000x reference)
//
#include <hip/hip_runtime.h>
#include <math.h>

#define D_MODEL 512
#define BATCH 8
#define SEQ 512
#define HEAD 64
#define DK 4
#define DV 8
#define HIDD 10

// proj tiled-GEMM params
#define MR 32    // rows per block (4 waves x 8 rows)
#define KC 32    // k-chunk
#define NC 256   // cols per block (W tile 32 KB LDS)

__device__ __forceinline__ float4 fma4(float s, float4 w, float4 a) {
    a.x = fmaf(s, w.x, a.x); a.y = fmaf(s, w.y, a.y);
    a.z = fmaf(s, w.z, a.z); a.w = fmaf(s, w.w, a.w);
    return a;
}

// ---------------------------------------------------------------------------
// 64x64-tile transpose (r4-proven): x[4096][512] -> xT[512][4096], ditto xe.
// ---------------------------------------------------------------------------
__global__ __launch_bounds__(256) void transpose_kernel(
    const float* __restrict__ x, const float* __restrict__ xe,
    float* __restrict__ xT, float* __restrict__ xeT)
{
    __shared__ float tile[64][65];
    int bid = blockIdx.x;
    const float* src; float* dst;
    if (bid < 512) { src = x;  dst = xT; }
    else           { src = xe; dst = xeT; bid -= 512; }
    const int R0 = (bid >> 3) * 64;
    const int C0 = (bid & 7) * 64;
    const int t = threadIdx.x;
    const int rr = t >> 4, c4 = (t & 15) * 4;
#pragma unroll
    for (int i = 0; i < 4; ++i) {
        const float4 v = *(const float4*)(src + (long)(R0 + i * 16 + rr) * 512 + C0 + c4);
        tile[i * 16 + rr][c4 + 0] = v.x; tile[i * 16 + rr][c4 + 1] = v.y;
        tile[i * 16 + rr][c4 + 2] = v.z; tile[i * 16 + rr][c4 + 3] = v.w;
    }
    __syncthreads();
#pragma unroll
    for (int i = 0; i < 4; ++i) {
        const int oc = i * 16 + rr;
        float4 v;
        v.x = tile[c4 + 0][oc]; v.y = tile[c4 + 1][oc];
        v.z = tile[c4 + 2][oc]; v.w = tile[c4 + 3][oc];
        *(float4*)(dst + (long)(C0 + oc) * 4096 + R0 + c4) = v;
    }
}

// ---------------------------------------------------------------------------
// proj v2: W tile in LDS (per-lane reads, 1 ds_read_b128/k); x read from
// GLOBAL at a wave-uniform address (xT[k][8 rows of wave rg] = 32 B = one
// cache transaction, VMEM pipe, vmcnt counter — no lgkm mixing with the
// W read). Removes 2 of 3 LDS insts/k + the whole x-staging phase:
// LDS/k/CU ~210 cyc < VALU 224 -> VALU-bound (was 504 -> LDS-bound 2.25x).
// x prefetched 1-deep: k+1 issued before k's 32 FMAs; the xa=xb rotation
// places the vmcnt wait after the FMA block.
// 7 col-jobs x 128 row-blocks = 896 blocks, 14 waves/CU. Head-major out.
// ---------------------------------------------------------------------------
__global__ __launch_bounds__(256) void proj_kernel(
    const float* __restrict__ xT, const float* __restrict__ xeT,
    const float* __restrict__ Wq, const float* __restrict__ Wk,
    const float* __restrict__ Wv,
    float* __restrict__ Q2, float* __restrict__ K2, float* __restrict__ V2,
    float* __restrict__ Kc, float* __restrict__ Vc)
{
    __shared__ float wt[KC * NC];   // 32 KB

    const int t  = threadIdx.x;
    const int bj = blockIdx.x >> 7;      // 0..6 col-job
    const int br = blockIdx.x & 127;     // row block
    const int r0 = br * MR;

    const float* XT; const float* W; int ldw; int c0; float* dst; int vt;
    switch (bj) {
      case 0:  XT = xT;  W = Wq; ldw = 256; c0 = 0;   dst = Q2; vt = 0; break;
      case 1:  XT = xT;  W = Wk; ldw = 256; c0 = 0;   dst = K2; vt = 0; break;
      case 2:  XT = xT;  W = Wv; ldw = 512; c0 = 0;   dst = V2; vt = 1; break;
      case 3:  XT = xT;  W = Wv; ldw = 512; c0 = 256; dst = V2; vt = 1; break;
      case 4:  XT = xeT; W = Wk; ldw = 256; c0 = 0;   dst = Kc; vt = 0; break;
      case 5:  XT = xeT; W = Wv; ldw = 512; c0 = 0;   dst = Vc; vt = 1; break;
      default: XT = xeT; W = Wv; ldw = 512; c0 = 256; dst = Vc; vt = 1; break;
    }

    const int rg = t >> 6;          // wave id -> rows rg*8..rg*8+7
    const int cq = t & 63;          // cols cq*4..cq*4+3
    const float* xp = XT + r0 + rg * 8;   // wave-uniform; + k*4096 per k

    float4 acc[8];
#pragma unroll
    for (int r = 0; r < 8; ++r) acc[r] = make_float4(0.f, 0.f, 0.f, 0.f);

    // prefetch k = 0
    float4 xa0 = *(const float4*)(xp);
    float4 xa1 = *(const float4*)(xp + 4);

    for (int kc = 0; kc < D_MODEL; kc += KC) {
        // ---- stage W tile: wave rg loads rows i*4+rg, 1 KB contiguous ----
#pragma unroll
        for (int i = 0; i < 8; ++i) {
            const int row = i * 4 + rg;
            *(float4*)(wt + row * NC + cq * 4) =
                *(const float4*)(W + (long)(kc + row) * ldw + c0 + cq * 4);
        }
        __syncthreads();

#pragma unroll 4
        for (int k = 0; k < KC; ++k) {
            const int kn = kc + k + 1;
            const float* xpn = xp + (long)(kn < 512 ? kn : 511) * 4096;
            const float4 xb0 = *(const float4*)(xpn);       // VMEM, in flight
            const float4 xb1 = *(const float4*)(xpn + 4);   // across the FMAs
            const float4 w4 = *(const float4*)(wt + k * NC + cq * 4);
            acc[0] = fma4(xa0.x, w4, acc[0]);
            acc[1] = fma4(xa0.y, w4, acc[1]);
            acc[2] = fma4(xa0.z, w4, acc[2]);
            acc[3] = fma4(xa0.w, w4, acc[3]);
            acc[4] = fma4(xa1.x, w4, acc[4]);
            acc[5] = fma4(xa1.y, w4, acc[5]);
            acc[6] = fma4(xa1.z, w4, acc[6]);
            acc[7] = fma4(xa1.w, w4, acc[7]);
            xa0 = xb0; xa1 = xb1;           // vmcnt wait lands here
        }
        __syncthreads();
    }

    // ---- epilogue: head-major scatter (r5-verbatim) ----
    const int b = r0 >> 9;
    const int sb = (r0 & 511) + rg * 8;
    if (vt == 0) {
#pragma unroll
        for (int r = 0; r < 8; ++r) {
            (void)r;
        }
        // rows: this wave owns rows sb..sb+7? No — per-thread tile is
        // 8 rows x 4 cols with rows = wave rows; each thread writes its col.
#pragma unroll
        for (int r = 0; r < 8; ++r)
            *(float4*)(dst + (((long)b * HEAD + cq) * SEQ + sb + r) * 4) = acc[r];
    } else {
        const int col = c0 + cq * 4;
        const int h = col >> 3;
        const int off = col & 7;        // 0 or 4
#pragma unroll
        for (int r = 0; r < 8; ++r)
            *(float4*)(dst + (((long)b * HEAD + h) * SEQ + sb + r) * 8 + off) = acc[r];
    }
}

// ---------------------------------------------------------------------------
// proj2 (r5-proven, FROZEN): Q only, split-K x2 (Qa + Qb; attn sums on load).
// ---------------------------------------------------------------------------
__global__ __launch_bounds__(256, 8) void proj2_kernel(
    const float* __restrict__ A, const float* __restrict__ Wq,
    float* __restrict__ Qa, float* __restrict__ Qb)
{
    __shared__ float xt[32 * 32];   // 4 KB
    __shared__ float wt[32 * 64];   // 8 KB

    const int t  = threadIdx.x;
    const int kh = blockIdx.x & 1;
    const int bj = (blockIdx.x >> 1) & 3;
    const int br = blockIdx.x >> 3;
    const int r0 = br * 32;
    const int c0 = bj * 64;
    const int kb = kh * 256;
    float* dst = kh ? Qb : Qa;

    const int cq = t & 15;
    const int rr = t >> 4;
    const int rs = t & 31, kq = t >> 5;

    float4 acc[2];
    acc[0] = make_float4(0.f, 0.f, 0.f, 0.f);
    acc[1] = acc[0];

    for (int kc = 0; kc < 256; kc += 32) {
        const float4 xa = *(const float4*)(A + (long)(r0 + rs) * D_MODEL + kb + kc + kq * 4);
        xt[(kq * 4 + 0) * 32 + rs] = xa.x;
        xt[(kq * 4 + 1) * 32 + rs] = xa.y;
        xt[(kq * 4 + 2) * 32 + rs] = xa.z;
        xt[(kq * 4 + 3) * 32 + rs] = xa.w;
#pragma unroll
        for (int i = 0; i < 2; ++i) {
            const int row = i * 16 + (t >> 4);
            *(float4*)(wt + row * 64 + (t & 15) * 4) =
                *(const float4*)(Wq + (long)(kb + kc + row) * 256 + c0 + (t & 15) * 4);
        }
        __syncthreads();
#pragma unroll 4
        for (int k = 0; k < 32; ++k) {
            const float4 w4 = *(const float4*)(wt + k * 64 + cq * 4);
            const float2 x2 = *(const float2*)(xt + k * 32 + rr * 2);
            acc[0] = fma4(x2.x, w4, acc[0]);
            acc[1] = fma4(x2.y, w4, acc[1]);
        }
        __syncthreads();
    }

    const int b  = r0 >> 9;
    const int sb = (r0 & 511) + rr * 2;
    const int h  = (c0 >> 2) + cq;
#pragma unroll
    for (int r = 0; r < 2; ++r)
        *(float4*)(dst + (((long)b * HEAD + h) * SEQ + sb + r) * 4) = acc[r];
}

// ---------------------------------------------------------------------------
// Attention v1 (r0/r5-proven, 75.6 us measured; FROZEN): one block per
// (b, h, q-half); 256 threads, 1 query/thread. Online softmax in the LOG2
// domain. Causal quirk preserved: masked scores are exactly 0 and
// participate; lump = 2^(-M) * (count, suffixSumV).
// ---------------------------------------------------------------------------
__global__ __launch_bounds__(256) void attn_kernel(
    const float* __restrict__ Qa, const float* __restrict__ Qb,
    const float* __restrict__ K2, const float* __restrict__ V2,
    float* __restrict__ O, int causal)
{
    extern __shared__ float smem[];
    float* Kl = smem;                 // SEQ*DK = 2048 floats
    float* Vl = smem + SEQ * DK;      // SEQ*DV = 4096 floats
    float* cs = Vl + SEQ * DV;        // 33*DV  =  264 floats (causal only)

    const int t = threadIdx.x;
    const int bh = blockIdx.x >> 1;
    const int qhalf = blockIdx.x & 1;
    const int b = bh >> 6;
    const int h = bh & 63;

    const float4* Ks = (const float4*)(K2 + (long)bh * SEQ * DK);
    ((float4*)Kl)[t]       = Ks[t];
    ((float4*)Kl)[t + 256] = Ks[t + 256];
    const float4* Vs = (const float4*)(V2 + (long)bh * SEQ * DV);
#pragma unroll
    for (int i = 0; i < 4; ++i)
        ((float4*)Vl)[t + i * 256] = Vs[t + i * 256];
    __syncthreads();

    if (causal) {
        const int ch = t >> 3, d = t & 7;
        float s16 = 0.f;
#pragma unroll
        for (int i = 0; i < 16; ++i) s16 += Vl[(ch * 16 + i) * 8 + d];
        cs[ch * 8 + d] = s16;
        __syncthreads();
        if (t < 8) {
            cs[256 + t] = 0.f;
            float run = 0.f;
            for (int c2 = 31; c2 >= 0; --c2) {
                run += cs[c2 * 8 + t];
                cs[c2 * 8 + t] = run;
            }
        }
        __syncthreads();
    }

    const int q = qhalf * 256 + t;
    float4 qv = *(const float4*)(Qa + ((long)bh * SEQ + q) * 4);
    if (Qb) {
        const float4 qw = *(const float4*)(Qb + ((long)bh * SEQ + q) * 4);
        qv.x += qw.x; qv.y += qw.y; qv.z += qw.z; qv.w += qw.w;
    }
    const float cf = 0.5f * 1.44269504088896340736f;  // 1/sqrt(DK) * log2(e)
    const float q0 = qv.x * cf, q1 = qv.y * cf;
    const float q2 = qv.z * cf, q3 = qv.w * cf;

    const int bound = causal ? q : (SEQ - 1);

    float m = -INFINITY, l = 0.f;
    float a0=0.f,a1=0.f,a2=0.f,a3=0.f,a4=0.f,a5=0.f,a6=0.f,a7=0.f;

    int s0 = 0;
    for (; s0 + 8 <= bound + 1; s0 += 8) {
        float sc[8];
#pragma unroll
        for (int i = 0; i < 8; ++i) {
            const float4 k4 = *(const float4*)(Kl + (s0 + i) * 4);
            sc[i] = fmaf(q0, k4.x, fmaf(q1, k4.y, fmaf(q2, k4.z, q3 * k4.w)));
        }
        float gm = fmaxf(fmaxf(fmaxf(sc[0], sc[1]), fmaxf(sc[2], sc[3])),
                         fmaxf(fmaxf(sc[4], sc[5]), fmaxf(sc[6], sc[7])));
        if (gm > m) {
            float scale = __builtin_amdgcn_exp2f(m - gm);
            l *= scale;
            a0*=scale; a1*=scale; a2*=scale; a3*=scale;
            a4*=scale; a5*=scale; a6*=scale; a7*=scale;
            m = gm;
        }
#pragma unroll
        for (int i = 0; i < 8; ++i) {
            float p = __builtin_amdgcn_exp2f(sc[i] - m);
            l += p;
            const float4 v0 = *(const float4*)(Vl + (s0 + i) * 8);
            const float4 v1 = *(const float4*)(Vl + (s0 + i) * 8 + 4);
            a0 = fmaf(p, v0.x, a0); a1 = fmaf(p, v0.y, a1);
            a2 = fmaf(p, v0.z, a2); a3 = fmaf(p, v0.w, a3);
            a4 = fmaf(p, v1.x, a4); a5 = fmaf(p, v1.y, a5);
            a6 = fmaf(p, v1.z, a6); a7 = fmaf(p, v1.w, a7);
        }
    }
    for (int s = s0; s <= bound; ++s) {
        const float4 k4 = *(const float4*)(Kl + s * 4);
        float sc = fmaf(q0, k4.x, fmaf(q1, k4.y, fmaf(q2, k4.z, q3 * k4.w)));
        if (sc > m) {
            float scale = __builtin_amdgcn_exp2f(m - sc);
            l *= scale;
            a0*=scale; a1*=scale; a2*=scale; a3*=scale;
            a4*=scale; a5*=scale; a6*=scale; a7*=scale;
            m = sc;
        }
        float p = __builtin_amdgcn_exp2f(sc - m);
        l += p;
        const float4 v0 = *(const float4*)(Vl + s * 8);
        const float4 v1 = *(const float4*)(Vl + s * 8 + 4);
        a0 = fmaf(p, v0.x, a0); a1 = fmaf(p, v0.y, a1);
        a2 = fmaf(p, v0.z, a2); a3 = fmaf(p, v0.w, a3);
        a4 = fmaf(p, v1.x, a4); a5 = fmaf(p, v1.y, a5);
        a6 = fmaf(p, v1.z, a6); a7 = fmaf(p, v1.w, a7);
    }

    if (causal && q < SEQ - 1) {
        float M = fmaxf(m, 0.f);
        float scale = __builtin_amdgcn_exp2f(m - M);
        float pm = __builtin_amdgcn_exp2f(-M);
        l = l * scale + pm * (float)(SEQ - 1 - q);
        int nq = q + 1;
        int cq2 = nq >> 4;
        float sv[8];
#pragma unroll
        for (int d = 0; d < 8; ++d) sv[d] = cs[(cq2 + 1) * 8 + d];
        for (int s = nq; s < (cq2 + 1) * 16; ++s) {
            const float4 v0 = *(const float4*)(Vl + s * 8);
            const float4 v1 = *(const float4*)(Vl + s * 8 + 4);
            sv[0]+=v0.x; sv[1]+=v0.y; sv[2]+=v0.z; sv[3]+=v0.w;
            sv[4]+=v1.x; sv[5]+=v1.y; sv[6]+=v1.z; sv[7]+=v1.w;
        }
        a0 = a0*scale + pm*sv[0]; a1 = a1*scale + pm*sv[1];
        a2 = a2*scale + pm*sv[2]; a3 = a3*scale + pm*sv[3];
        a4 = a4*scale + pm*sv[4]; a5 = a5*scale + pm*sv[5];
        a6 = a6*scale + pm*sv[6]; a7 = a7*scale + pm*sv[7];
    }

    float inv = 1.0f / l;
    const long obase = (long)b * SEQ * 512 + (long)q * 512 + h * DV;
    *(float4*)(O + obase)     = make_float4(a0*inv, a1*inv, a2*inv, a3*inv);
    *(float4*)(O + obase + 4) = make_float4(a4*inv, a5*inv, a6*inv, a7*inv);
}

// ---------------------------------------------------------------------------
// Fused residual + LayerNorm + MLP (512 -> 10 -> 512), r5-proven, FROZEN.
// ---------------------------------------------------------------------------
__global__ __launch_bounds__(256) void ln_mlp_kernel(
    const float* __restrict__ x, const float* __restrict__ fx,
    const float* __restrict__ g, const float* __restrict__ beta,
    const float* __restrict__ w1, const float* __restrict__ b1,
    const float* __restrict__ w2, const float* __restrict__ b2,
    float* __restrict__ out)
{
    const int t = threadIdx.x;
    const int lane = t & 63;
    const int row = blockIdx.x * 4 + (t >> 6);
    const long base = (long)row * D_MODEL;
    const int e0 = lane * 8;

    const float4 xa = *(const float4*)(x + base + e0);
    const float4 xb = *(const float4*)(x + base + e0 + 4);
    const float4 fa = *(const float4*)(fx + base + e0);
    const float4 fb = *(const float4*)(fx + base + e0 + 4);
    float z[8] = {xa.x+fa.x, xa.y+fa.y, xa.z+fa.z, xa.w+fa.w,
                  xb.x+fb.x, xb.y+fb.y, xb.z+fb.z, xb.w+fb.w};

    float sum = 0.f;
#pragma unroll
    for (int j = 0; j < 8; ++j) sum += z[j];
#pragma unroll
    for (int o = 32; o > 0; o >>= 1) sum += __shfl_xor(sum, o);
    float mu = sum * (1.0f / 512.0f);

    float d[8], ss = 0.f;
#pragma unroll
    for (int j = 0; j < 8; ++j) { d[j] = z[j] - mu; ss += d[j] * d[j]; }
#pragma unroll
    for (int o = 32; o > 0; o >>= 1) ss += __shfl_xor(ss, o);
    float rs = rsqrtf(ss * (1.0f / 512.0f) + 1e-5f);

    const float4 ga = *(const float4*)(g + e0);
    const float4 gb = *(const float4*)(g + e0 + 4);
    const float4 ba = *(const float4*)(beta + e0);
    const float4 bb = *(const float4*)(beta + e0 + 4);
    const float gg[8] = {ga.x,ga.y,ga.z,ga.w,gb.x,gb.y,gb.z,gb.w};
    const float bt[8] = {ba.x,ba.y,ba.z,ba.w,bb.x,bb.y,bb.z,bb.w};
    float y[8];
#pragma unroll
    for (int j = 0; j < 8; ++j) y[j] = d[j] * rs * gg[j] + bt[j];

    float part[HIDD];
#pragma unroll
    for (int i = 0; i < HIDD; ++i) {
        const float4 wa = *(const float4*)(w1 + i * 512 + e0);
        const float4 wb = *(const float4*)(w1 + i * 512 + e0 + 4);
        part[i] = y[0]*wa.x + y[1]*wa.y + y[2]*wa.z + y[3]*wa.w
                + y[4]*wb.x + y[5]*wb.y + y[6]*wb.z + y[7]*wb.w;
    }
#pragma unroll
    for (int i = 0; i < HIDD; ++i)
#pragma unroll
        for (int o = 32; o > 0; o >>= 1) part[i] += __shfl_xor(part[i], o);

    float hv[HIDD];
#pragma unroll
    for (int i = 0; i < HIDD; ++i) hv[i] = fmaxf(part[i] + b1[i], 0.f);

    float o8[8];
#pragma unroll
    for (int j = 0; j < 8; ++j) o8[j] = b2[e0 + j];
#pragma unroll
    for (int i = 0; i < HIDD; ++i)
#pragma unroll
        for (int j = 0; j < 8; ++j)
            o8[j] = fmaf(hv[i], w2[(long)(e0 + j) * 10 + i], o8[j]);

    *(float4*)(out + base + e0)     = make_float4(o8[0], o8[1], o8[2], o8[3]);
    *(float4*)(out + base + e0 + 4) = make_float4(o8[4], o8[5], o8[6], o8[7]);
}

extern "C" void kernel_launch(void* const* d_in, const int* in_sizes, int n_in,
                              void* d_out, int out_size, void* d_ws, size_t ws_size,
                              hipStream_t stream) {
    (void)in_sizes; (void)n_in; (void)out_size; (void)ws_size;
    const float* x    = (const float*)d_in[0];
    const float* xenc = (const float*)d_in[1];
    const float* Wq   = (const float*)d_in[2];
    const float* Wk   = (const float*)d_in[3];
    const float* Wv   = (const float*)d_in[4];
    const float* ln_g = (const float*)d_in[5];
    const float* ln_b = (const float*)d_in[6];
    const float* w1   = (const float*)d_in[7];
    const float* b1   = (const float*)d_in[8];
    const float* w2   = (const float*)d_in[9];
    const float* b2   = (const float*)d_in[10];
    float* out = (float*)d_out;

    // Workspace: 11M floats = 44 MiB. Liveness-verified aliasing:
    //   transpose: w xT[0,2) xeT[2,4)
    //   proj1:     r xT,xeT        w Q1[4,5) K1[5,6) V1[6,8) Kc[8,9) Vc[9,11)
    //   attn1:     r Q1,K1,V1      w A[0,2)   (xT dead)
    //   proj2:     r A             w Qa[2,3) Qb[3,4)  (xeT dead)
    //   attn2:     r Qa,Qb,Kc,Vc   w A[0,2)   (attn1's A dead after proj2)
    //   ln_mlp:    r x,A           w out
    float* ws  = (float*)d_ws;
    float* xT  = ws;                   // [ 0M, 2M)
    float* xeT = ws + 2097152;         // [ 2M, 4M)
    float* Q1  = ws + 4194304;         // [ 4M, 5M)
    float* K1  = ws + 5242880;         // [ 5M, 6M)
    float* V1  = ws + 6291456;         // [ 6M, 8M)
    float* Kc  = ws + 8388608;         // [ 8M, 9M)
    float* Vc  = ws + 9437184;         // [ 9M,11M)
    float* A   = ws;                   // [ 0M, 2M)
    float* Qa  = ws + 2097152;         // [ 2M, 3M)
    float* Qb  = ws + 3145728;         // [ 3M, 4M)

    const size_t lds_cross  = (size_t)(SEQ * DK + SEQ * DV) * 4;          // 24576
    const size_t lds_causal = lds_cross + (size_t)(33 * DV) * 4;          // 25632

    transpose_kernel<<<dim3(1024), 256, 0, stream>>>(x, xenc, xT, xeT);
    proj_kernel<<<dim3(896), 256, 0, stream>>>(xT, xeT, Wq, Wk, Wv,
                                               Q1, K1, V1, Kc, Vc);
    attn_kernel<<<dim3(BATCH * HEAD * 2), 256, lds_causal, stream>>>(
        Q1, nullptr, K1, V1, A, 1);
    proj2_kernel<<<dim3(1024), 256, 0, stream>>>(A, Wq, Qa, Qb);
    attn_kernel<<<dim3(BATCH * HEAD * 2), 256, lds_cross, stream>>>(
        Qa, Qb, Kc, Vc, A, 0);
    ln_mlp_kernel<<<dim3(1024), 256, 0, stream>>>(x, A, ln_g, ln_b,
                                                  w1, b1, w2, b2, out);
}